// Round 11
// baseline (620.827 us; speedup 1.0000x reference)
//
#include <hip/hip_runtime.h>
#include <hip/hip_bf16.h>
#include <hip/hip_cooperative_groups.h>

namespace cg = cooperative_groups;

// GCN VGAE encoder as ONE cooperative kernel (phases split by grid.sync), with a
// multi-kernel fallback if the cooperative launch is rejected.
//   P0 zero ccur | P1 bin (register-cached, bucket=col>>6) | P2 fine sort -> CSR
//   P3 gemm1 -> bf16 planes | P4 gather1 (both planes) | P5 gemm2 | P6 gather2 -> out
// ALL phases are grid-stride: correct for any grid size (R10's NaN was phase
// guards assuming grid >= 782 blocks).
// norm factorization: agg[c] = dinv[c]*(sum_e ts[src] + ts[c]) + b, ts = (X@W)*dinv.

constexpr int SH = 6;            // nodes per coarse bucket = 64
constexpr int CAP = 4096;        // slab capacity per bucket (mean ~2046, 45 sigma)
constexpr int BMAX = 1024;       // max coarse buckets (N <= 65536)
constexpr int EPB = 8;           // register-cached edges/thread in bin (chunk 2048)
constexpr int EPT = 10;          // register-cached edges/thread in fine

typedef float vf4 __attribute__((ext_vector_type(4)));   // for nontemporal stores

__device__ __forceinline__ void fma4(float4& a, float s, const float4& w) {
    a.x = fmaf(s, w.x, a.x);
    a.y = fmaf(s, w.y, a.y);
    a.z = fmaf(s, w.z, a.z);
    a.w = fmaf(s, w.w, a.w);
}

__device__ __forceinline__ unsigned short f2bf(float f) {  // RNE
    unsigned u = __float_as_uint(f);
    return (unsigned short)((u + 0x7fffu + ((u >> 16) & 1u)) >> 16);
}

__device__ __forceinline__ void acc_bf8(float* a, uint4 v) {
    a[0] += __uint_as_float(v.x << 16);
    a[1] += __uint_as_float(v.x & 0xffff0000u);
    a[2] += __uint_as_float(v.y << 16);
    a[3] += __uint_as_float(v.y & 0xffff0000u);
    a[4] += __uint_as_float(v.z << 16);
    a[5] += __uint_as_float(v.z & 0xffff0000u);
    a[6] += __uint_as_float(v.w << 16);
    a[7] += __uint_as_float(v.w & 0xffff0000u);
}

// One (node,quad) of a 32-feat plane gather. 8-edge unroll for MLP.
template <bool NT>
__device__ __forceinline__ void gather_one(const int2* __restrict__ range2,
                                           const unsigned short* __restrict__ srcidx,
                                           const uint4* __restrict__ Tp,
                                           const float* __restrict__ dinv,
                                           const float* __restrict__ bias,
                                           float* __restrict__ dst, int n, int q) {
    int2 rg = range2[n];
    int k = rg.x, end = rg.y;
    float a[8];
    {
        uint4 s = Tp[(size_t)n * 4 + q];   // self loop
        a[0] = __uint_as_float(s.x << 16);
        a[1] = __uint_as_float(s.x & 0xffff0000u);
        a[2] = __uint_as_float(s.y << 16);
        a[3] = __uint_as_float(s.y & 0xffff0000u);
        a[4] = __uint_as_float(s.z << 16);
        a[5] = __uint_as_float(s.z & 0xffff0000u);
        a[6] = __uint_as_float(s.w << 16);
        a[7] = __uint_as_float(s.w & 0xffff0000u);
    }
    for (; k < end && (k & 3); ++k)          // align to ushort4
        acc_bf8(a, Tp[(size_t)srcidx[k] * 4 + q]);
    for (; k + 8 <= end; k += 8) {
        ushort4 r0 = *reinterpret_cast<const ushort4*>(srcidx + k);
        ushort4 r1 = *reinterpret_cast<const ushort4*>(srcidx + k + 4);
        uint4 v0 = Tp[(size_t)r0.x * 4 + q];
        uint4 v1 = Tp[(size_t)r0.y * 4 + q];
        uint4 v2 = Tp[(size_t)r0.z * 4 + q];
        uint4 v3 = Tp[(size_t)r0.w * 4 + q];
        uint4 v4 = Tp[(size_t)r1.x * 4 + q];
        uint4 v5 = Tp[(size_t)r1.y * 4 + q];
        uint4 v6 = Tp[(size_t)r1.z * 4 + q];
        uint4 v7 = Tp[(size_t)r1.w * 4 + q];
        acc_bf8(a, v0); acc_bf8(a, v1); acc_bf8(a, v2); acc_bf8(a, v3);
        acc_bf8(a, v4); acc_bf8(a, v5); acc_bf8(a, v6); acc_bf8(a, v7);
    }
    if (k + 4 <= end) {
        ushort4 r0 = *reinterpret_cast<const ushort4*>(srcidx + k);
        uint4 v0 = Tp[(size_t)r0.x * 4 + q];
        uint4 v1 = Tp[(size_t)r0.y * 4 + q];
        uint4 v2 = Tp[(size_t)r0.z * 4 + q];
        uint4 v3 = Tp[(size_t)r0.w * 4 + q];
        acc_bf8(a, v0); acc_bf8(a, v1); acc_bf8(a, v2); acc_bf8(a, v3);
        k += 4;
    }
    for (; k < end; ++k)
        acc_bf8(a, Tp[(size_t)srcidx[k] * 4 + q]);

    float d = dinv[n];
    float4 b0 = reinterpret_cast<const float4*>(bias + q * 8)[0];
    float4 b1 = reinterpret_cast<const float4*>(bias + q * 8)[1];
    vf4 o0, o1;
    o0.x = fmaf(a[0], d, b0.x); o0.y = fmaf(a[1], d, b0.y);
    o0.z = fmaf(a[2], d, b0.z); o0.w = fmaf(a[3], d, b0.w);
    o1.x = fmaf(a[4], d, b1.x); o1.y = fmaf(a[5], d, b1.y);
    o1.z = fmaf(a[6], d, b1.z); o1.w = fmaf(a[7], d, b1.w);
    vf4* dp = reinterpret_cast<vf4*>(dst + (size_t)n * 32 + q * 8);
    if (NT) {
        __builtin_nontemporal_store(o0, dp);
        __builtin_nontemporal_store(o1, dp + 1);
    } else {
        dp[0] = o0;
        dp[1] = o1;
    }
}

// One 64-node tile: T planes (bf16 [N][32] x2) = (op(X) @ W) * dinv. W in LDS.
// PIN: X given as two fp32 [N][32] planes (layer 2); else contiguous [N][K].
template <int K, bool RELU, bool PIN>
__device__ __forceinline__ void gemm_tile(const float4* __restrict__ Wl,
                                          const float* __restrict__ X,
                                          const float* __restrict__ Xhi,
                                          const float* __restrict__ dinv,
                                          unsigned short* __restrict__ Tlo,
                                          unsigned short* __restrict__ Thi,
                                          int N, int nb, int tid) {
    const int fg = tid & 15;
    const int ns = tid >> 4;
    const float4* Xv = reinterpret_cast<const float4*>(X);
    const float4* Xv2 = reinterpret_cast<const float4*>(Xhi);
    const float4 z = make_float4(0.f, 0.f, 0.f, 0.f);
    float4 acc[4] = {z, z, z, z};
    int n[4];
    bool v[4];
    #pragma unroll
    for (int i = 0; i < 4; ++i) { n[i] = nb + ns + i * 16; v[i] = n[i] < N; }

    for (int k4 = 0; k4 < K / 4; ++k4) {
        float4 xv[4];
        #pragma unroll
        for (int i = 0; i < 4; ++i) {
            if (PIN)
                xv[i] = v[i] ? ((k4 < 8) ? Xv[(size_t)n[i] * 8 + k4]
                                         : Xv2[(size_t)n[i] * 8 + (k4 - 8)]) : z;
            else
                xv[i] = v[i] ? Xv[(size_t)n[i] * (K / 4) + k4] : z;
            if (RELU) {
                xv[i].x = fmaxf(xv[i].x, 0.f); xv[i].y = fmaxf(xv[i].y, 0.f);
                xv[i].z = fmaxf(xv[i].z, 0.f); xv[i].w = fmaxf(xv[i].w, 0.f);
            }
        }
        float4 w0 = Wl[(k4 * 4 + 0) * 16 + fg];
        float4 w1 = Wl[(k4 * 4 + 1) * 16 + fg];
        float4 w2 = Wl[(k4 * 4 + 2) * 16 + fg];
        float4 w3 = Wl[(k4 * 4 + 3) * 16 + fg];
        #pragma unroll
        for (int i = 0; i < 4; ++i) {
            fma4(acc[i], xv[i].x, w0); fma4(acc[i], xv[i].y, w1);
            fma4(acc[i], xv[i].z, w2); fma4(acc[i], xv[i].w, w3);
        }
    }
    ushort4* Tp = reinterpret_cast<ushort4*>((fg < 8) ? Tlo : Thi);
    const int j = fg & 7;
    #pragma unroll
    for (int i = 0; i < 4; ++i) {
        if (v[i]) {
            float d = dinv[n[i]];
            ushort4 o;
            o.x = f2bf(acc[i].x * d); o.y = f2bf(acc[i].y * d);
            o.z = f2bf(acc[i].z * d); o.w = f2bf(acc[i].w * d);
            Tp[(size_t)n[i] * 8 + j] = o;
        }
    }
}

// ---------------- cooperative mega-kernel ----------------

__global__ __launch_bounds__(256, 4) void k_mega(
    const int* row, const int* col, const float* x,
    const float* W1, const float* b1,
    const float* Wmu, const float* bmu,
    const float* Wls, const float* bls,
    int* ccur, unsigned* binned, unsigned short* srcidx,
    float* dinv, int2* range2,
    unsigned short* t_lo, unsigned short* t_hi,
    float* agg_lo, float* agg_hi, float* outp,
    int N, int E, int B) {
    cg::grid_group grid = cg::this_grid();
    __shared__ __align__(16) char smraw[32768];   // union: hist/fine | Wl[K*16]
    int* hist = reinterpret_cast<int*>(smraw);
    float4* Wl = reinterpret_cast<float4*>(smraw);
    const int tid = threadIdx.x;
    const int blk = blockIdx.x;
    const int nblk = (int)gridDim.x;

    // ---- P0: zero bucket cursors (grid-stride) ----
    for (int i = blk * 256 + tid; i < BMAX; i += nblk * 256) ccur[i] = 0;
    grid.sync();

    // ---- P1: bin edges (col16<<16|row16) into bucket slabs ----
    {
        for (int i = tid; i < B; i += 256) hist[i] = 0;
        __syncthreads();
        const int ch = (E + nblk - 1) / nblk;
        const int e0 = blk * ch;
        const int e1 = min(e0 + ch, E);
        unsigned ebuf[EPB];
        #pragma unroll
        for (int j = 0; j < EPB; ++j) {
            int e = e0 + tid + j * 256;
            ebuf[j] = (e < e1) ? (((unsigned)col[e] << 16) | (unsigned)row[e])
                               : 0xFFFFFFFFu;
        }
        #pragma unroll
        for (int j = 0; j < EPB; ++j)
            if (ebuf[j] != 0xFFFFFFFFu) atomicAdd(&hist[ebuf[j] >> 22], 1);
        for (int e = e0 + EPB * 256 + tid; e < e1; e += 256)   // tail if ch > 2048
            atomicAdd(&hist[(unsigned)col[e] >> SH], 1);
        __syncthreads();
        for (int i = tid; i < B; i += 256) {
            int c = hist[i];
            if (c) hist[i] = atomicAdd(&ccur[i], c);
        }
        __syncthreads();
        #pragma unroll
        for (int j = 0; j < EPB; ++j) {
            unsigned e = ebuf[j];
            if (e != 0xFFFFFFFFu) {
                int b = e >> 22;
                int pos = atomicAdd(&hist[b], 1);
                if (pos < CAP) binned[(size_t)b * CAP + pos] = e;
            }
        }
        for (int i = e0 + EPB * 256 + tid; i < e1; i += 256) {
            unsigned e = ((unsigned)col[i] << 16) | (unsigned)row[i];
            int b = e >> 22;
            int pos = atomicAdd(&hist[b], 1);
            if (pos < CAP) binned[(size_t)b * CAP + pos] = e;
        }
    }
    grid.sync();

    // ---- P2: fine sort buckets -> ushort srcidx + range2 + dinv (grid-stride) ----
    for (int bb = blk; bb < B; bb += nblk) {
        int* fine = hist;   // 64 counters
        const int n0 = bb << SH;
        const int ebase = bb * CAP;
        const int ecnt = min(ccur[bb], CAP);
        if (tid < 64) fine[tid] = 0;
        __syncthreads();
        unsigned ebuf[EPT];
        #pragma unroll
        for (int j = 0; j < EPT; ++j) {
            int i = tid + j * 256;
            ebuf[j] = (i < ecnt) ? binned[ebase + i] : 0xFFFFFFFFu;
        }
        #pragma unroll
        for (int j = 0; j < EPT; ++j)
            if (ebuf[j] != 0xFFFFFFFFu) atomicAdd(&fine[(ebuf[j] >> 16) & 63], 1);
        for (int i = EPT * 256 + tid; i < ecnt; i += 256)
            atomicAdd(&fine[(binned[ebase + i] >> 16) & 63], 1);
        __syncthreads();
        if (tid < 64) {
            int v = fine[tid], s = v;
            #pragma unroll
            for (int off = 1; off < 64; off <<= 1) {
                int u = __shfl_up(s, off, 64);
                if (tid >= off) s += u;
            }
            int base = ebase + s - v;
            int n = n0 + tid;
            if (n < N) {
                range2[n] = make_int2(base, base + v);
                dinv[n] = rsqrtf((float)v + 1.0f);
            }
            fine[tid] = base;
        }
        __syncthreads();
        #pragma unroll
        for (int j = 0; j < EPT; ++j) {
            unsigned e = ebuf[j];
            if (e != 0xFFFFFFFFu) {
                int pos = atomicAdd(&fine[(e >> 16) & 63], 1);
                srcidx[pos] = (unsigned short)(e & 0xFFFFu);
            }
        }
        for (int i = EPT * 256 + tid; i < ecnt; i += 256) {
            unsigned e = binned[ebase + i];
            int pos = atomicAdd(&fine[(e >> 16) & 63], 1);
            srcidx[pos] = (unsigned short)(e & 0xFFFFu);
        }
        __syncthreads();   // LDS reused next iteration
    }
    grid.sync();

    const int ntiles = (N + 63) >> 6;

    // ---- P3: gemm1 (x @ W1) * dinv -> bf16 planes (grid-stride tiles) ----
    {
        for (int i = tid; i < 128 * 16; i += 256)
            Wl[i] = reinterpret_cast<const float4*>(W1)[i];
        __syncthreads();
        for (int t = blk; t < ntiles; t += nblk)
            gemm_tile<128, false, false>(Wl, x, nullptr, dinv, t_lo, t_hi, N,
                                         t * 64, tid);
    }
    grid.sync();

    // ---- P4: gather layer 1 (both planes) -> agg planes (fp32) ----
    {
        const int Nq = N * 4;
        for (int u = blk * 256 + tid; u < 2 * Nq; u += nblk * 256) {
            bool hi = u >= Nq;
            int idx = hi ? u - Nq : u;
            gather_one<false>(range2, srcidx,
                              reinterpret_cast<const uint4*>(hi ? t_hi : t_lo), dinv,
                              hi ? b1 + 32 : b1, hi ? agg_hi : agg_lo,
                              idx >> 2, idx & 3);
        }
    }
    grid.sync();

    // ---- P5: gemm2 relu(agg) @ [Wmu|Wls] * dinv -> bf16 planes ----
    {
        for (int i = tid; i < 64 * 16; i += 256) {
            int k = i >> 4, fgi = i & 15;
            const float* s = (fgi < 8) ? (Wmu + k * 32 + fgi * 4)
                                       : (Wls + k * 32 + (fgi - 8) * 4);
            Wl[i] = *reinterpret_cast<const float4*>(s);
        }
        __syncthreads();
        for (int t = blk; t < ntiles; t += nblk)
            gemm_tile<64, true, true>(Wl, agg_lo, agg_hi, dinv, t_lo, t_hi, N,
                                      t * 64, tid);
    }
    grid.sync();

    // ---- P6: gather layer 2 -> out (mu | logstd), nontemporal ----
    {
        const int Nq = N * 4;
        for (int u = blk * 256 + tid; u < 2 * Nq; u += nblk * 256) {
            bool hi = u >= Nq;
            int idx = hi ? u - Nq : u;
            gather_one<true>(range2, srcidx,
                             reinterpret_cast<const uint4*>(hi ? t_hi : t_lo), dinv,
                             hi ? bls : bmu, hi ? outp + 32 * (size_t)N : outp,
                             idx >> 2, idx & 3);
        }
    }
}

// ---------------- fallback multi-kernel pipeline (R9, known-good) ----------------

__global__ __launch_bounds__(256) void k_bin(const int* __restrict__ row,
                                             const int* __restrict__ col,
                                             int* __restrict__ ccur,
                                             unsigned* __restrict__ binned,
                                             int E, int B) {
    __shared__ int h[BMAX];
    const int tid = threadIdx.x;
    for (int i = tid; i < B; i += 256) h[i] = 0;
    __syncthreads();
    const int e0 = blockIdx.x * 2048;
    const int e1 = min(e0 + 2048, E);
    unsigned ebuf[EPB];
    #pragma unroll
    for (int j = 0; j < EPB; ++j) {
        int e = e0 + tid + j * 256;
        ebuf[j] = (e < e1) ? (((unsigned)col[e] << 16) | (unsigned)row[e]) : 0xFFFFFFFFu;
    }
    #pragma unroll
    for (int j = 0; j < EPB; ++j)
        if (ebuf[j] != 0xFFFFFFFFu) atomicAdd(&h[ebuf[j] >> 22], 1);
    __syncthreads();
    for (int i = tid; i < B; i += 256) {
        int c = h[i];
        if (c) h[i] = atomicAdd(&ccur[i], c);
    }
    __syncthreads();
    #pragma unroll
    for (int j = 0; j < EPB; ++j) {
        unsigned e = ebuf[j];
        if (e != 0xFFFFFFFFu) {
            int b = e >> 22;
            int pos = atomicAdd(&h[b], 1);
            if (pos < CAP) binned[(size_t)b * CAP + pos] = e;
        }
    }
}

__global__ __launch_bounds__(256) void k_fine(const unsigned* __restrict__ binned,
                                              const int* __restrict__ ccur,
                                              unsigned short* __restrict__ srcidx,
                                              int2* __restrict__ range2,
                                              float* __restrict__ dinv, int N) {
    __shared__ int fine[64];
    const int b = blockIdx.x;
    const int n0 = b << SH;
    const int ebase = b * CAP;
    int ecnt = min(ccur[b], CAP);
    const int tid = threadIdx.x;
    if (tid < 64) fine[tid] = 0;
    __syncthreads();
    unsigned ebuf[EPT];
    #pragma unroll
    for (int j = 0; j < EPT; ++j) {
        int i = tid + j * 256;
        ebuf[j] = (i < ecnt) ? binned[ebase + i] : 0xFFFFFFFFu;
    }
    #pragma unroll
    for (int j = 0; j < EPT; ++j)
        if (ebuf[j] != 0xFFFFFFFFu) atomicAdd(&fine[(ebuf[j] >> 16) & 63], 1);
    for (int i = EPT * 256 + tid; i < ecnt; i += 256)
        atomicAdd(&fine[(binned[ebase + i] >> 16) & 63], 1);
    __syncthreads();
    if (tid < 64) {
        int v = fine[tid], s = v;
        #pragma unroll
        for (int off = 1; off < 64; off <<= 1) {
            int u = __shfl_up(s, off, 64);
            if (tid >= off) s += u;
        }
        int base = ebase + s - v;
        int n = n0 + tid;
        if (n < N) {
            range2[n] = make_int2(base, base + v);
            dinv[n] = rsqrtf((float)v + 1.0f);
        }
        fine[tid] = base;
    }
    __syncthreads();
    #pragma unroll
    for (int j = 0; j < EPT; ++j) {
        unsigned e = ebuf[j];
        if (e != 0xFFFFFFFFu) {
            int pos = atomicAdd(&fine[(e >> 16) & 63], 1);
            srcidx[pos] = (unsigned short)(e & 0xFFFFu);
        }
    }
    for (int i = EPT * 256 + tid; i < ecnt; i += 256) {
        unsigned e = binned[ebase + i];
        int pos = atomicAdd(&fine[(e >> 16) & 63], 1);
        srcidx[pos] = (unsigned short)(e & 0xFFFFu);
    }
}

template <int K, bool RELU, bool TWO_W, bool PIN>
__global__ __launch_bounds__(256) void k_gemm(const float* __restrict__ X,
                                              const float* __restrict__ Xhi,
                                              const float* __restrict__ Wa,
                                              const float* __restrict__ Wb,
                                              const float* __restrict__ dinv,
                                              unsigned short* __restrict__ Tlo,
                                              unsigned short* __restrict__ Thi, int N) {
    __shared__ float4 Wl[K * 16];
    const int tid = threadIdx.x;
    for (int i = tid; i < K * 16; i += 256) {
        if (TWO_W) {
            int k = i >> 4, fgi = i & 15;
            const float* s = (fgi < 8) ? (Wa + k * 32 + fgi * 4)
                                       : (Wb + k * 32 + (fgi - 8) * 4);
            Wl[i] = *reinterpret_cast<const float4*>(s);
        } else {
            Wl[i] = reinterpret_cast<const float4*>(Wa)[i];
        }
    }
    __syncthreads();
    gemm_tile<K, RELU, PIN>(Wl, X, Xhi, dinv, Tlo, Thi, N, blockIdx.x * 64, tid);
}

template <bool NT>
__global__ __launch_bounds__(256) void k_gather(const int2* __restrict__ range2,
                                                const unsigned short* __restrict__ srcidx,
                                                const uint4* __restrict__ Tp,
                                                const float* __restrict__ dinv,
                                                const float* __restrict__ bias,
                                                float* __restrict__ dst, int N) {
    int g = blockIdx.x * 256 + threadIdx.x;
    if (g >= N * 4) return;
    gather_one<NT>(range2, srcidx, Tp, dinv, bias, dst, g >> 2, g & 3);
}

extern "C" void kernel_launch(void* const* d_in, const int* in_sizes, int n_in,
                              void* d_out, int out_size, void* d_ws, size_t ws_size,
                              hipStream_t stream) {
    const float* x   = (const float*)d_in[0];
    const int*   ei  = (const int*)d_in[1];
    const float* W1  = (const float*)d_in[2];
    const float* b1  = (const float*)d_in[3];
    const float* Wmu = (const float*)d_in[4];
    const float* bmu = (const float*)d_in[5];
    const float* Wls = (const float*)d_in[6];
    const float* bls = (const float*)d_in[7];

    const int N = in_sizes[0] / 128;
    const int E = in_sizes[1] / 2;
    const int* row = ei;            // sources
    const int* col = ei + E;        // targets
    const int B = (N + 63) >> SH;   // coarse buckets (<= BMAX)
    const size_t BCAP = (size_t)B * CAP;

    // ws layout (4B units):
    // [0,1024) ccur | [1024, 1024+ov) binned (overlaid after fine by the two bf16 ts
    // planes, each 16N ints) | srcidx ushort[BCAP] (BCAP/2 ints) | dinv[N] |
    // range2 int2[N] (2N) | agg_lo f32[32N] | agg_hi f32[32N]
    int* wsi = (int*)d_ws;
    int*  ccur   = wsi;
    unsigned* binned = (unsigned*)(wsi + 1024);
    unsigned short* t_lo = (unsigned short*)(wsi + 1024);
    unsigned short* t_hi = (unsigned short*)(wsi + 1024 + 16 * (size_t)N);
    size_t ov = BCAP > (size_t)32 * N ? BCAP : (size_t)32 * N;
    unsigned short* srcidx = (unsigned short*)(wsi + 1024 + ov);
    float* dinv  = (float*)(wsi + 1024 + ov + BCAP / 2);
    int2* range2 = (int2*)(dinv + N);
    float* agg_lo = (float*)(range2 + N);
    float* agg_hi = agg_lo + 32 * (size_t)N;
    float* outp  = (float*)d_out;

    int maxBpc = 0;
    if (hipOccupancyMaxActiveBlocksPerMultiprocessor(&maxBpc, k_mega, 256, 0)
            != hipSuccess || maxBpc <= 0)
        maxBpc = 2;
    long nbl = (long)maxBpc * 256;          // 256 CUs on MI355X
    int nb = (int)(nbl > 1024 ? 1024 : nbl);

    void* args[] = {
        (void*)&row, (void*)&col, (void*)&x, (void*)&W1, (void*)&b1,
        (void*)&Wmu, (void*)&bmu, (void*)&Wls, (void*)&bls,
        (void*)&ccur, (void*)&binned, (void*)&srcidx, (void*)&dinv, (void*)&range2,
        (void*)&t_lo, (void*)&t_hi, (void*)&agg_lo, (void*)&agg_hi, (void*)&outp,
        (void*)&N, (void*)&E, (void*)&B,
    };
    hipError_t err = hipLaunchCooperativeKernel((void*)k_mega, dim3(nb), dim3(256),
                                                args, 0, stream);
    if (err != hipSuccess) {
        // Deterministic fallback: known-good multi-kernel pipeline.
        const int G = (E + 2047) / 2048;
        const int ntiles = (N + 63) / 64;
        const int GG = (N * 4 + 255) / 256;
        (void)hipMemsetAsync(ccur, 0, BMAX * sizeof(int), stream);
        k_bin<<<G, 256, 0, stream>>>(row, col, ccur, binned, E, B);
        k_fine<<<B, 256, 0, stream>>>(binned, ccur, srcidx, range2, dinv, N);
        k_gemm<128, false, false, false><<<ntiles, 256, 0, stream>>>(
            x, nullptr, W1, nullptr, dinv, t_lo, t_hi, N);
        k_gather<false><<<GG, 256, 0, stream>>>(
            range2, srcidx, (const uint4*)t_lo, dinv, b1, agg_lo, N);
        k_gather<false><<<GG, 256, 0, stream>>>(
            range2, srcidx, (const uint4*)t_hi, dinv, b1 + 32, agg_hi, N);
        k_gemm<64, true, true, true><<<ntiles, 256, 0, stream>>>(
            agg_lo, agg_hi, Wmu, Wls, dinv, t_lo, t_hi, N);
        k_gather<true><<<GG, 256, 0, stream>>>(
            range2, srcidx, (const uint4*)t_lo, dinv, bmu, outp, N);
        k_gather<true><<<GG, 256, 0, stream>>>(
            range2, srcidx, (const uint4*)t_hi, dinv, bls, outp + 32 * (size_t)N, N);
    }
}

// Round 12
// 278.903 us; speedup vs baseline: 2.2260x; 2.2260x over previous
//
#include <hip/hip_runtime.h>
#include <hip/hip_bf16.h>

// GCN VGAE encoder, 4 kernels + memset (fusion along within-block chains):
//   k_bin        : single-read register-cached bucket binning (bucket = col>>6)
//   k_finegemm1  : per-bucket fine sort -> CSR(+dinv in LDS) -> gemm1 tile -> t1 planes
//   k_gathergemm2: per-tile gather layer1 into LDS agg (+b1, relu) -> gemm2 -> t2 planes
//   k_gather2    : gather layer2 (both planes) -> out (mu | logstd)
// norm factorization: agg[c] = dinv[c]*(sum_e ts[src] + ts[c]) + b, ts = (X@W)*dinv.
// Cooperative fusion (R11) regressed: grid.sync ~75us each on 8-XCD MI355X.

constexpr int SH = 6;            // nodes per coarse bucket = 64 (bucket == gemm tile)
constexpr int CAP = 4096;        // slab capacity per bucket (mean ~2046, 45 sigma)
constexpr int BMAX = 1024;       // max coarse buckets (N <= 65536)
constexpr int CHUNK = 2048;      // edges per block in k_bin
constexpr int EPB = CHUNK / 256; // 8 register-cached edges/thread in k_bin
constexpr int EPT = 10;          // register-cached edges/thread in fine phase

typedef float vf4 __attribute__((ext_vector_type(4)));   // for nontemporal stores

__device__ __forceinline__ void fma4(float4& a, float s, const float4& w) {
    a.x = fmaf(s, w.x, a.x);
    a.y = fmaf(s, w.y, a.y);
    a.z = fmaf(s, w.z, a.z);
    a.w = fmaf(s, w.w, a.w);
}

__device__ __forceinline__ unsigned short f2bf(float f) {  // RNE
    unsigned u = __float_as_uint(f);
    return (unsigned short)((u + 0x7fffu + ((u >> 16) & 1u)) >> 16);
}

__device__ __forceinline__ void acc_bf8(float* a, uint4 v) {
    a[0] += __uint_as_float(v.x << 16);
    a[1] += __uint_as_float(v.x & 0xffff0000u);
    a[2] += __uint_as_float(v.y << 16);
    a[3] += __uint_as_float(v.y & 0xffff0000u);
    a[4] += __uint_as_float(v.z << 16);
    a[5] += __uint_as_float(v.z & 0xffff0000u);
    a[6] += __uint_as_float(v.w << 16);
    a[7] += __uint_as_float(v.w & 0xffff0000u);
}

// Sum of one (node, quad) stripe of a 32-feat bf16 plane into a[8] (fp32),
// including the self loop. 8-edge unroll for MLP.
__device__ __forceinline__ void gather_core(const int2* __restrict__ range2,
                                            const unsigned short* __restrict__ srcidx,
                                            const uint4* __restrict__ Tp,
                                            int n, int q, float* a) {
    int2 rg = range2[n];
    int k = rg.x, end = rg.y;
    {
        uint4 s = Tp[(size_t)n * 4 + q];   // self loop
        a[0] = __uint_as_float(s.x << 16);
        a[1] = __uint_as_float(s.x & 0xffff0000u);
        a[2] = __uint_as_float(s.y << 16);
        a[3] = __uint_as_float(s.y & 0xffff0000u);
        a[4] = __uint_as_float(s.z << 16);
        a[5] = __uint_as_float(s.z & 0xffff0000u);
        a[6] = __uint_as_float(s.w << 16);
        a[7] = __uint_as_float(s.w & 0xffff0000u);
    }
    for (; k < end && (k & 3); ++k)          // align to ushort4
        acc_bf8(a, Tp[(size_t)srcidx[k] * 4 + q]);
    for (; k + 8 <= end; k += 8) {
        ushort4 r0 = *reinterpret_cast<const ushort4*>(srcidx + k);
        ushort4 r1 = *reinterpret_cast<const ushort4*>(srcidx + k + 4);
        uint4 v0 = Tp[(size_t)r0.x * 4 + q];
        uint4 v1 = Tp[(size_t)r0.y * 4 + q];
        uint4 v2 = Tp[(size_t)r0.z * 4 + q];
        uint4 v3 = Tp[(size_t)r0.w * 4 + q];
        uint4 v4 = Tp[(size_t)r1.x * 4 + q];
        uint4 v5 = Tp[(size_t)r1.y * 4 + q];
        uint4 v6 = Tp[(size_t)r1.z * 4 + q];
        uint4 v7 = Tp[(size_t)r1.w * 4 + q];
        acc_bf8(a, v0); acc_bf8(a, v1); acc_bf8(a, v2); acc_bf8(a, v3);
        acc_bf8(a, v4); acc_bf8(a, v5); acc_bf8(a, v6); acc_bf8(a, v7);
    }
    if (k + 4 <= end) {
        ushort4 r0 = *reinterpret_cast<const ushort4*>(srcidx + k);
        uint4 v0 = Tp[(size_t)r0.x * 4 + q];
        uint4 v1 = Tp[(size_t)r0.y * 4 + q];
        uint4 v2 = Tp[(size_t)r0.z * 4 + q];
        uint4 v3 = Tp[(size_t)r0.w * 4 + q];
        acc_bf8(a, v0); acc_bf8(a, v1); acc_bf8(a, v2); acc_bf8(a, v3);
        k += 4;
    }
    for (; k < end; ++k)
        acc_bf8(a, Tp[(size_t)srcidx[k] * 4 + q]);
}

// ---------------- k_bin ----------------
__global__ __launch_bounds__(256) void k_bin(const int* __restrict__ row,
                                             const int* __restrict__ col,
                                             int* __restrict__ ccur,
                                             unsigned* __restrict__ binned,
                                             int E, int B) {
    __shared__ int h[BMAX];
    const int tid = threadIdx.x;
    for (int i = tid; i < B; i += 256) h[i] = 0;
    __syncthreads();
    const int e0 = blockIdx.x * CHUNK;
    unsigned ebuf[EPB];
    #pragma unroll
    for (int j = 0; j < EPB; ++j) {
        int e = e0 + tid + j * 256;
        ebuf[j] = (e < E) ? (((unsigned)col[e] << 16) | (unsigned)row[e]) : 0xFFFFFFFFu;
    }
    #pragma unroll
    for (int j = 0; j < EPB; ++j)
        if (ebuf[j] != 0xFFFFFFFFu) atomicAdd(&h[ebuf[j] >> 22], 1);
    __syncthreads();
    for (int i = tid; i < B; i += 256) {
        int c = h[i];
        if (c) h[i] = atomicAdd(&ccur[i], c);   // in-bucket base for this block
    }
    __syncthreads();
    #pragma unroll
    for (int j = 0; j < EPB; ++j) {
        unsigned e = ebuf[j];
        if (e != 0xFFFFFFFFu) {
            int b = e >> 22;
            int pos = atomicAdd(&h[b], 1);
            if (pos < CAP) binned[(size_t)b * CAP + pos] = e;
        }
    }
}

// ---------------- k_finegemm1 ----------------
// Block b: fine-sort bucket b (nodes [64b,64b+64)) -> srcidx/range2/dinv (d2 in LDS),
// then gemm1 tile: t1 planes = (x[64b..] @ W1) * dinv.
__global__ __launch_bounds__(256) void k_finegemm1(
    const unsigned* __restrict__ binned, const int* __restrict__ ccur,
    const float* __restrict__ x, const float* __restrict__ W1,
    unsigned short* __restrict__ srcidx, int2* __restrict__ range2,
    float* __restrict__ dinv,
    unsigned short* __restrict__ t_lo, unsigned short* __restrict__ t_hi, int N) {
    __shared__ float4 Wl[128 * 16];   // 32 KB
    __shared__ int fine[64];
    __shared__ float d2[64];
    const int b = blockIdx.x;
    const int n0 = b << SH;
    const int ebase = b * CAP;
    const int ecnt = min(ccur[b], CAP);
    const int tid = threadIdx.x;

    for (int i = tid; i < 128 * 16; i += 256)
        Wl[i] = reinterpret_cast<const float4*>(W1)[i];
    if (tid < 64) fine[tid] = 0;
    __syncthreads();

    unsigned ebuf[EPT];
    #pragma unroll
    for (int j = 0; j < EPT; ++j) {
        int i = tid + j * 256;
        ebuf[j] = (i < ecnt) ? binned[ebase + i] : 0xFFFFFFFFu;
    }
    #pragma unroll
    for (int j = 0; j < EPT; ++j)
        if (ebuf[j] != 0xFFFFFFFFu) atomicAdd(&fine[(ebuf[j] >> 16) & 63], 1);
    for (int i = EPT * 256 + tid; i < ecnt; i += 256)   // overflow tail
        atomicAdd(&fine[(binned[ebase + i] >> 16) & 63], 1);
    __syncthreads();
    if (tid < 64) {
        int v = fine[tid], s = v;
        #pragma unroll
        for (int off = 1; off < 64; off <<= 1) {
            int u = __shfl_up(s, off, 64);
            if (tid >= off) s += u;
        }
        int base = ebase + s - v;
        float dv = rsqrtf((float)v + 1.0f);
        d2[tid] = dv;
        int n = n0 + tid;
        if (n < N) {
            range2[n] = make_int2(base, base + v);
            dinv[n] = dv;
        }
        fine[tid] = base;
    }
    __syncthreads();
    #pragma unroll
    for (int j = 0; j < EPT; ++j) {
        unsigned e = ebuf[j];
        if (e != 0xFFFFFFFFu) {
            int pos = atomicAdd(&fine[(e >> 16) & 63], 1);
            srcidx[pos] = (unsigned short)(e & 0xFFFFu);
        }
    }
    for (int i = EPT * 256 + tid; i < ecnt; i += 256) {
        unsigned e = binned[ebase + i];
        int pos = atomicAdd(&fine[(e >> 16) & 63], 1);
        srcidx[pos] = (unsigned short)(e & 0xFFFFu);
    }
    __syncthreads();

    // gemm1 tile: 4 nodes/thread, K=128
    const int fg = tid & 15;
    const int ns = tid >> 4;
    const float4* Xv = reinterpret_cast<const float4*>(x);
    const float4 z = make_float4(0.f, 0.f, 0.f, 0.f);
    float4 acc[4] = {z, z, z, z};
    int n[4];
    bool v[4];
    #pragma unroll
    for (int i = 0; i < 4; ++i) { n[i] = n0 + ns + i * 16; v[i] = n[i] < N; }
    for (int k4 = 0; k4 < 32; ++k4) {
        float4 xv[4];
        #pragma unroll
        for (int i = 0; i < 4; ++i) xv[i] = v[i] ? Xv[(size_t)n[i] * 32 + k4] : z;
        float4 w0 = Wl[(k4 * 4 + 0) * 16 + fg];
        float4 w1 = Wl[(k4 * 4 + 1) * 16 + fg];
        float4 w2 = Wl[(k4 * 4 + 2) * 16 + fg];
        float4 w3 = Wl[(k4 * 4 + 3) * 16 + fg];
        #pragma unroll
        for (int i = 0; i < 4; ++i) {
            fma4(acc[i], xv[i].x, w0); fma4(acc[i], xv[i].y, w1);
            fma4(acc[i], xv[i].z, w2); fma4(acc[i], xv[i].w, w3);
        }
    }
    ushort4* Tp = reinterpret_cast<ushort4*>((fg < 8) ? t_lo : t_hi);
    const int j = fg & 7;
    #pragma unroll
    for (int i = 0; i < 4; ++i) {
        if (v[i]) {
            float d = d2[ns + i * 16];
            ushort4 o;
            o.x = f2bf(acc[i].x * d); o.y = f2bf(acc[i].y * d);
            o.z = f2bf(acc[i].z * d); o.w = f2bf(acc[i].w * d);
            Tp[(size_t)n[i] * 8 + j] = o;
        }
    }
}

// ---------------- k_gathergemm2 ----------------
// Block t: gather layer1 for nodes [64t,64t+64) (both planes) into LDS agg
// (bias+relu applied), then gemm2 tile from LDS -> t2 planes.
__global__ __launch_bounds__(256) void k_gathergemm2(
    const int2* __restrict__ range2, const unsigned short* __restrict__ srcidx,
    const uint4* __restrict__ t1_lo, const uint4* __restrict__ t1_hi,
    const float* __restrict__ dinv, const float* __restrict__ b1,
    const float* __restrict__ Wmu, const float* __restrict__ Wls,
    unsigned short* __restrict__ t2_lo, unsigned short* __restrict__ t2_hi, int N) {
    __shared__ float4 Wl[64 * 16];    // 16 KB
    __shared__ float agg[64 * 68];    // 17.4 KB, row pad 68 (16B-aligned rows)
    __shared__ float d2[64];
    const int tile = blockIdx.x;
    const int n0 = tile << 6;
    const int tid = threadIdx.x;

    for (int i = tid; i < 64 * 16; i += 256) {
        int k = i >> 4, fgi = i & 15;
        const float* s = (fgi < 8) ? (Wmu + k * 32 + fgi * 4)
                                   : (Wls + k * 32 + (fgi - 8) * 4);
        Wl[i] = *reinterpret_cast<const float4*>(s);
    }

    // gather both planes into LDS agg with +b1 and relu
    for (int u = tid; u < 512; u += 256) {
        int nl = u >> 3;             // 0..63
        int n = n0 + nl;
        int q8 = u & 7;              // plane*4 + quad
        if (n < N) {
            const uint4* Tp = (q8 < 4) ? t1_lo : t1_hi;
            int q = q8 & 3;
            float a[8];
            gather_core(range2, srcidx, Tp, n, q, a);
            float d = dinv[n];
            if (q8 == 0) d2[nl] = d;
            int f0 = ((q8 < 4) ? 0 : 32) + q * 8;
            const float* bs = b1 + f0;
            float* dst = &agg[nl * 68 + f0];
            #pragma unroll
            for (int j = 0; j < 8; ++j)
                dst[j] = fmaxf(fmaf(a[j], d, bs[j]), 0.f);
        }
    }
    __syncthreads();

    // gemm2 tile: K=64 from LDS agg
    const int fg = tid & 15;
    const int ns = tid >> 4;
    const float4 z = make_float4(0.f, 0.f, 0.f, 0.f);
    float4 acc[4] = {z, z, z, z};
    int nl[4];
    bool v[4];
    #pragma unroll
    for (int i = 0; i < 4; ++i) { nl[i] = ns + i * 16; v[i] = (n0 + nl[i]) < N; }
    for (int k4 = 0; k4 < 16; ++k4) {
        float4 xv[4];
        #pragma unroll
        for (int i = 0; i < 4; ++i)
            xv[i] = *reinterpret_cast<const float4*>(&agg[nl[i] * 68 + k4 * 4]);
        float4 w0 = Wl[(k4 * 4 + 0) * 16 + fg];
        float4 w1 = Wl[(k4 * 4 + 1) * 16 + fg];
        float4 w2 = Wl[(k4 * 4 + 2) * 16 + fg];
        float4 w3 = Wl[(k4 * 4 + 3) * 16 + fg];
        #pragma unroll
        for (int i = 0; i < 4; ++i) {
            fma4(acc[i], xv[i].x, w0); fma4(acc[i], xv[i].y, w1);
            fma4(acc[i], xv[i].z, w2); fma4(acc[i], xv[i].w, w3);
        }
    }
    ushort4* Tp = reinterpret_cast<ushort4*>((fg < 8) ? t2_lo : t2_hi);
    const int j = fg & 7;
    #pragma unroll
    for (int i = 0; i < 4; ++i) {
        if (v[i]) {
            float d = d2[nl[i]];
            ushort4 o;
            o.x = f2bf(acc[i].x * d); o.y = f2bf(acc[i].y * d);
            o.z = f2bf(acc[i].z * d); o.w = f2bf(acc[i].w * d);
            Tp[(size_t)(n0 + nl[i]) * 8 + j] = o;
        }
    }
}

// ---------------- k_gather2 ----------------
// Both output planes in one dispatch: g < N*4 -> mu (t2_lo), else logstd (t2_hi).
__global__ __launch_bounds__(256) void k_gather2(
    const int2* __restrict__ range2, const unsigned short* __restrict__ srcidx,
    const uint4* __restrict__ t2_lo, const uint4* __restrict__ t2_hi,
    const float* __restrict__ dinv,
    const float* __restrict__ bmu, const float* __restrict__ bls,
    float* __restrict__ outp, int N) {
    int g = blockIdx.x * 256 + threadIdx.x;
    const int Nq = N * 4;
    if (g >= 2 * Nq) return;
    bool hi = g >= Nq;
    int idx = hi ? g - Nq : g;
    int n = idx >> 2, q = idx & 3;
    float a[8];
    gather_core(range2, srcidx, hi ? t2_hi : t2_lo, n, q, a);
    float d = dinv[n];
    const float* bias = (hi ? bls : bmu) + q * 8;
    float* dst = (hi ? outp + 32 * (size_t)N : outp) + (size_t)n * 32 + q * 8;
    float4 b0 = reinterpret_cast<const float4*>(bias)[0];
    float4 b1 = reinterpret_cast<const float4*>(bias)[1];
    vf4 o0, o1;
    o0.x = fmaf(a[0], d, b0.x); o0.y = fmaf(a[1], d, b0.y);
    o0.z = fmaf(a[2], d, b0.z); o0.w = fmaf(a[3], d, b0.w);
    o1.x = fmaf(a[4], d, b1.x); o1.y = fmaf(a[5], d, b1.y);
    o1.z = fmaf(a[6], d, b1.z); o1.w = fmaf(a[7], d, b1.w);
    __builtin_nontemporal_store(o0, reinterpret_cast<vf4*>(dst));
    __builtin_nontemporal_store(o1, reinterpret_cast<vf4*>(dst) + 1);
}

extern "C" void kernel_launch(void* const* d_in, const int* in_sizes, int n_in,
                              void* d_out, int out_size, void* d_ws, size_t ws_size,
                              hipStream_t stream) {
    const float* x   = (const float*)d_in[0];
    const int*   ei  = (const int*)d_in[1];
    const float* W1  = (const float*)d_in[2];
    const float* b1  = (const float*)d_in[3];
    const float* Wmu = (const float*)d_in[4];
    const float* bmu = (const float*)d_in[5];
    const float* Wls = (const float*)d_in[6];
    const float* bls = (const float*)d_in[7];

    const int N = in_sizes[0] / 128;
    const int E = in_sizes[1] / 2;
    const int* row = ei;            // sources
    const int* col = ei + E;        // targets
    const int B = (N + 63) >> SH;   // coarse buckets == 64-node tiles
    const size_t BCAP = (size_t)B * CAP;
    const size_t PL = (size_t)16 * N;   // one bf16 [N][32] plane, in 4B units

    // ws layout (4B units), no overlays:
    // ccur[1024] | binned[BCAP] | srcidx ushort[BCAP] (BCAP/2) |
    // t1_lo[PL] | t1_hi[PL] | t2_lo[PL] | t2_hi[PL] | dinv[N] | range2 int2[N]
    int* wsi = (int*)d_ws;
    size_t off = 0;
    int* ccur = wsi + off;                              off += 1024;
    unsigned* binned = (unsigned*)(wsi + off);          off += BCAP;
    unsigned short* srcidx = (unsigned short*)(wsi + off); off += BCAP / 2;
    unsigned short* t1_lo = (unsigned short*)(wsi + off);  off += PL;
    unsigned short* t1_hi = (unsigned short*)(wsi + off);  off += PL;
    unsigned short* t2_lo = (unsigned short*)(wsi + off);  off += PL;
    unsigned short* t2_hi = (unsigned short*)(wsi + off);  off += PL;
    float* dinv = (float*)(wsi + off);                  off += N;
    int2* range2 = (int2*)(wsi + off);                  off += 2 * (size_t)N;
    float* outp = (float*)d_out;

    (void)hipMemsetAsync(ccur, 0, 1024 * sizeof(int), stream);
    k_bin<<<(E + CHUNK - 1) / CHUNK, 256, 0, stream>>>(row, col, ccur, binned, E, B);
    k_finegemm1<<<B, 256, 0, stream>>>(binned, ccur, x, W1, srcidx, range2, dinv,
                                       t1_lo, t1_hi, N);
    k_gathergemm2<<<B, 256, 0, stream>>>(range2, srcidx, (const uint4*)t1_lo,
                                         (const uint4*)t1_hi, dinv, b1, Wmu, Wls,
                                         t2_lo, t2_hi, N);
    k_gather2<<<(2 * N * 4 + 255) / 256, 256, 0, stream>>>(
        range2, srcidx, (const uint4*)t2_lo, (const uint4*)t2_hi, dinv,
        bmu, bls, outp, N);
}

// Round 13
// 244.879 us; speedup vs baseline: 2.5352x; 1.1389x over previous
//
#include <hip/hip_runtime.h>
#include <hip/hip_bf16.h>

// GCN VGAE encoder, 7 dispatches (R9 kernels, per-layer gathers merged):
//   memset ccur | k_bin | k_fine | k_gemm1 | k_gather<L1 both planes> |
//   k_gemm2 | k_gather<L2 both planes -> out>
// norm factorization: agg[c] = dinv[c]*(sum_e ts[src] + ts[c]) + b, ts = (X@W)*dinv.
// Fusion notes: coop grid.sync ~75us each on 8-XCD MI355X (R11); block-fusing
// gather+gemm blows VGPRs to 236 and chokes occupancy (R12). Keep kernels split.

constexpr int SH = 6;            // nodes per coarse bucket = 64
constexpr int CAP = 4096;        // slab capacity per bucket (mean ~2046, 45 sigma)
constexpr int BMAX = 1024;       // max coarse buckets (N <= 65536)
constexpr int CHUNK = 2048;      // edges per block in k_bin (782 blocks ~ 3/CU)
constexpr int EPB = CHUNK / 256; // 8 register-cached edges/thread in k_bin
constexpr int EPT = 10;          // register-cached edges/thread in k_fine

typedef float vf4 __attribute__((ext_vector_type(4)));   // for nontemporal stores

__device__ __forceinline__ void fma4(float4& a, float s, const float4& w) {
    a.x = fmaf(s, w.x, a.x);
    a.y = fmaf(s, w.y, a.y);
    a.z = fmaf(s, w.z, a.z);
    a.w = fmaf(s, w.w, a.w);
}

__device__ __forceinline__ unsigned short f2bf(float f) {  // RNE
    unsigned u = __float_as_uint(f);
    return (unsigned short)((u + 0x7fffu + ((u >> 16) & 1u)) >> 16);
}

__device__ __forceinline__ void acc_bf8(float* a, uint4 v) {
    a[0] += __uint_as_float(v.x << 16);
    a[1] += __uint_as_float(v.x & 0xffff0000u);
    a[2] += __uint_as_float(v.y << 16);
    a[3] += __uint_as_float(v.y & 0xffff0000u);
    a[4] += __uint_as_float(v.z << 16);
    a[5] += __uint_as_float(v.z & 0xffff0000u);
    a[6] += __uint_as_float(v.w << 16);
    a[7] += __uint_as_float(v.w & 0xffff0000u);
}

// Sum of one (node, quad) stripe of a 32-feat bf16 plane into a[8] (fp32),
// including the self loop. 8-edge unroll for MLP.
__device__ __forceinline__ void gather_core(const int2* __restrict__ range2,
                                            const unsigned short* __restrict__ srcidx,
                                            const uint4* __restrict__ Tp,
                                            int n, int q, float* a) {
    int2 rg = range2[n];
    int k = rg.x, end = rg.y;
    {
        uint4 s = Tp[(size_t)n * 4 + q];   // self loop
        a[0] = __uint_as_float(s.x << 16);
        a[1] = __uint_as_float(s.x & 0xffff0000u);
        a[2] = __uint_as_float(s.y << 16);
        a[3] = __uint_as_float(s.y & 0xffff0000u);
        a[4] = __uint_as_float(s.z << 16);
        a[5] = __uint_as_float(s.z & 0xffff0000u);
        a[6] = __uint_as_float(s.w << 16);
        a[7] = __uint_as_float(s.w & 0xffff0000u);
    }
    for (; k < end && (k & 3); ++k)          // align to ushort4
        acc_bf8(a, Tp[(size_t)srcidx[k] * 4 + q]);
    for (; k + 8 <= end; k += 8) {
        ushort4 r0 = *reinterpret_cast<const ushort4*>(srcidx + k);
        ushort4 r1 = *reinterpret_cast<const ushort4*>(srcidx + k + 4);
        uint4 v0 = Tp[(size_t)r0.x * 4 + q];
        uint4 v1 = Tp[(size_t)r0.y * 4 + q];
        uint4 v2 = Tp[(size_t)r0.z * 4 + q];
        uint4 v3 = Tp[(size_t)r0.w * 4 + q];
        uint4 v4 = Tp[(size_t)r1.x * 4 + q];
        uint4 v5 = Tp[(size_t)r1.y * 4 + q];
        uint4 v6 = Tp[(size_t)r1.z * 4 + q];
        uint4 v7 = Tp[(size_t)r1.w * 4 + q];
        acc_bf8(a, v0); acc_bf8(a, v1); acc_bf8(a, v2); acc_bf8(a, v3);
        acc_bf8(a, v4); acc_bf8(a, v5); acc_bf8(a, v6); acc_bf8(a, v7);
    }
    if (k + 4 <= end) {
        ushort4 r0 = *reinterpret_cast<const ushort4*>(srcidx + k);
        uint4 v0 = Tp[(size_t)r0.x * 4 + q];
        uint4 v1 = Tp[(size_t)r0.y * 4 + q];
        uint4 v2 = Tp[(size_t)r0.z * 4 + q];
        uint4 v3 = Tp[(size_t)r0.w * 4 + q];
        acc_bf8(a, v0); acc_bf8(a, v1); acc_bf8(a, v2); acc_bf8(a, v3);
        k += 4;
    }
    for (; k < end; ++k)
        acc_bf8(a, Tp[(size_t)srcidx[k] * 4 + q]);
}

// ---------------- k_bin ----------------
// Single global read; edges register-cached as col16<<16|row16; LDS hist ->
// reserve slab slice via ccur atomic -> emit. Bucket = packed>>22.
__global__ __launch_bounds__(256) void k_bin(const int* __restrict__ row,
                                             const int* __restrict__ col,
                                             int* __restrict__ ccur,
                                             unsigned* __restrict__ binned,
                                             int E, int B) {
    __shared__ int h[BMAX];
    const int tid = threadIdx.x;
    for (int i = tid; i < B; i += 256) h[i] = 0;
    __syncthreads();
    const int e0 = blockIdx.x * CHUNK;
    unsigned ebuf[EPB];
    #pragma unroll
    for (int j = 0; j < EPB; ++j) {
        int e = e0 + tid + j * 256;
        ebuf[j] = (e < E) ? (((unsigned)col[e] << 16) | (unsigned)row[e]) : 0xFFFFFFFFu;
    }
    #pragma unroll
    for (int j = 0; j < EPB; ++j)
        if (ebuf[j] != 0xFFFFFFFFu) atomicAdd(&h[ebuf[j] >> 22], 1);
    __syncthreads();
    for (int i = tid; i < B; i += 256) {
        int c = h[i];
        if (c) h[i] = atomicAdd(&ccur[i], c);   // in-bucket base for this block
    }
    __syncthreads();
    #pragma unroll
    for (int j = 0; j < EPB; ++j) {
        unsigned e = ebuf[j];
        if (e != 0xFFFFFFFFu) {
            int b = e >> 22;
            int pos = atomicAdd(&h[b], 1);
            if (pos < CAP) binned[(size_t)b * CAP + pos] = e;
        }
    }
}

// ---------------- k_fine ----------------
// One block per bucket: register-cached entries; fine histogram -> dinv +
// (start,end) ranges; dense ushort srcidx emit into the bucket's slab.
__global__ __launch_bounds__(256) void k_fine(const unsigned* __restrict__ binned,
                                              const int* __restrict__ ccur,
                                              unsigned short* __restrict__ srcidx,
                                              int2* __restrict__ range2,
                                              float* __restrict__ dinv, int N) {
    __shared__ int fine[64];
    const int b = blockIdx.x;
    const int n0 = b << SH;
    const int ebase = b * CAP;
    int ecnt = min(ccur[b], CAP);
    const int tid = threadIdx.x;
    if (tid < 64) fine[tid] = 0;
    __syncthreads();
    unsigned ebuf[EPT];
    #pragma unroll
    for (int j = 0; j < EPT; ++j) {
        int i = tid + j * 256;
        ebuf[j] = (i < ecnt) ? binned[ebase + i] : 0xFFFFFFFFu;
    }
    #pragma unroll
    for (int j = 0; j < EPT; ++j)
        if (ebuf[j] != 0xFFFFFFFFu) atomicAdd(&fine[(ebuf[j] >> 16) & 63], 1);
    for (int i = EPT * 256 + tid; i < ecnt; i += 256)   // overflow tail
        atomicAdd(&fine[(binned[ebase + i] >> 16) & 63], 1);
    __syncthreads();
    if (tid < 64) {
        int v = fine[tid], s = v;
        #pragma unroll
        for (int off = 1; off < 64; off <<= 1) {
            int u = __shfl_up(s, off, 64);
            if (tid >= off) s += u;
        }
        int base = ebase + s - v;
        int n = n0 + tid;
        if (n < N) {
            range2[n] = make_int2(base, base + v);
            dinv[n] = rsqrtf((float)v + 1.0f);
        }
        fine[tid] = base;
    }
    __syncthreads();
    #pragma unroll
    for (int j = 0; j < EPT; ++j) {
        unsigned e = ebuf[j];
        if (e != 0xFFFFFFFFu) {
            int pos = atomicAdd(&fine[(e >> 16) & 63], 1);
            srcidx[pos] = (unsigned short)(e & 0xFFFFu);
        }
    }
    for (int i = EPT * 256 + tid; i < ecnt; i += 256) {
        unsigned e = binned[ebase + i];
        int pos = atomicAdd(&fine[(e >> 16) & 63], 1);
        srcidx[pos] = (unsigned short)(e & 0xFFFFu);
    }
}

// ---------------- k_gemm ----------------
// T planes (bf16 [N][32] x2) = (op(X) @ W) * dinv[n]. 4 nodes/thread.
// PIN: X given as two fp32 [N][32] planes (layer 2); else contiguous [N][K].
template <int K, bool RELU, bool TWO_W, bool PIN>
__global__ __launch_bounds__(256) void k_gemm(const float* __restrict__ X,
                                              const float* __restrict__ Xhi,
                                              const float* __restrict__ Wa,
                                              const float* __restrict__ Wb,
                                              const float* __restrict__ dinv,
                                              unsigned short* __restrict__ Tlo,
                                              unsigned short* __restrict__ Thi, int N) {
    __shared__ float4 Wl[K * 16];
    const int tid = threadIdx.x;
    for (int i = tid; i < K * 16; i += 256) {
        if (TWO_W) {
            int k = i >> 4, fgi = i & 15;
            const float* s = (fgi < 8) ? (Wa + k * 32 + fgi * 4)
                                       : (Wb + k * 32 + (fgi - 8) * 4);
            Wl[i] = *reinterpret_cast<const float4*>(s);
        } else {
            Wl[i] = reinterpret_cast<const float4*>(Wa)[i];
        }
    }
    __syncthreads();

    const int fg = tid & 15;
    const int ns = tid >> 4;
    const int nb = blockIdx.x * 64;
    const float4* Xv = reinterpret_cast<const float4*>(X);
    const float4* Xv2 = reinterpret_cast<const float4*>(Xhi);
    const float4 z = make_float4(0.f, 0.f, 0.f, 0.f);
    float4 acc[4] = {z, z, z, z};
    int n[4];
    bool v[4];
    #pragma unroll
    for (int i = 0; i < 4; ++i) { n[i] = nb + ns + i * 16; v[i] = n[i] < N; }

    for (int k4 = 0; k4 < K / 4; ++k4) {
        float4 xv[4];
        #pragma unroll
        for (int i = 0; i < 4; ++i) {
            if (PIN)
                xv[i] = v[i] ? ((k4 < 8) ? Xv[(size_t)n[i] * 8 + k4]
                                         : Xv2[(size_t)n[i] * 8 + (k4 - 8)]) : z;
            else
                xv[i] = v[i] ? Xv[(size_t)n[i] * (K / 4) + k4] : z;
            if (RELU) {
                xv[i].x = fmaxf(xv[i].x, 0.f); xv[i].y = fmaxf(xv[i].y, 0.f);
                xv[i].z = fmaxf(xv[i].z, 0.f); xv[i].w = fmaxf(xv[i].w, 0.f);
            }
        }
        float4 w0 = Wl[(k4 * 4 + 0) * 16 + fg];
        float4 w1 = Wl[(k4 * 4 + 1) * 16 + fg];
        float4 w2 = Wl[(k4 * 4 + 2) * 16 + fg];
        float4 w3 = Wl[(k4 * 4 + 3) * 16 + fg];
        #pragma unroll
        for (int i = 0; i < 4; ++i) {
            fma4(acc[i], xv[i].x, w0); fma4(acc[i], xv[i].y, w1);
            fma4(acc[i], xv[i].z, w2); fma4(acc[i], xv[i].w, w3);
        }
    }
    ushort4* Tp = reinterpret_cast<ushort4*>((fg < 8) ? Tlo : Thi);
    const int j = fg & 7;
    #pragma unroll
    for (int i = 0; i < 4; ++i) {
        if (v[i]) {
            float d = dinv[n[i]];
            ushort4 o;
            o.x = f2bf(acc[i].x * d); o.y = f2bf(acc[i].y * d);
            o.z = f2bf(acc[i].z * d); o.w = f2bf(acc[i].w * d);
            Tp[(size_t)n[i] * 8 + j] = o;
        }
    }
}

// ---------------- k_gather ----------------
// Both planes of one layer in a single dispatch: g < N*4 -> lo plane, else hi.
// dst planes are separate pointers (L1: agg_lo/agg_hi fp32; L2: mu/logstd halves
// of d_out, nontemporal).
template <bool NT>
__global__ __launch_bounds__(256) void k_gather(
    const int2* __restrict__ range2, const unsigned short* __restrict__ srcidx,
    const uint4* __restrict__ Tlo, const uint4* __restrict__ Thi,
    const float* __restrict__ dinv,
    const float* __restrict__ bias_lo, const float* __restrict__ bias_hi,
    float* __restrict__ dst_lo, float* __restrict__ dst_hi, int N) {
    int g = blockIdx.x * 256 + threadIdx.x;
    const int Nq = N * 4;
    if (g >= 2 * Nq) return;
    bool hi = g >= Nq;
    int idx = hi ? g - Nq : g;
    int n = idx >> 2, q = idx & 3;
    float a[8];
    gather_core(range2, srcidx, hi ? Thi : Tlo, n, q, a);
    float d = dinv[n];
    const float* bias = (hi ? bias_hi : bias_lo) + q * 8;
    float* dst = (hi ? dst_hi : dst_lo) + (size_t)n * 32 + q * 8;
    float4 b0 = reinterpret_cast<const float4*>(bias)[0];
    float4 b1 = reinterpret_cast<const float4*>(bias)[1];
    vf4 o0, o1;
    o0.x = fmaf(a[0], d, b0.x); o0.y = fmaf(a[1], d, b0.y);
    o0.z = fmaf(a[2], d, b0.z); o0.w = fmaf(a[3], d, b0.w);
    o1.x = fmaf(a[4], d, b1.x); o1.y = fmaf(a[5], d, b1.y);
    o1.z = fmaf(a[6], d, b1.z); o1.w = fmaf(a[7], d, b1.w);
    if (NT) {
        __builtin_nontemporal_store(o0, reinterpret_cast<vf4*>(dst));
        __builtin_nontemporal_store(o1, reinterpret_cast<vf4*>(dst) + 1);
    } else {
        reinterpret_cast<vf4*>(dst)[0] = o0;
        reinterpret_cast<vf4*>(dst)[1] = o1;
    }
}

extern "C" void kernel_launch(void* const* d_in, const int* in_sizes, int n_in,
                              void* d_out, int out_size, void* d_ws, size_t ws_size,
                              hipStream_t stream) {
    const float* x   = (const float*)d_in[0];
    const int*   ei  = (const int*)d_in[1];
    const float* W1  = (const float*)d_in[2];
    const float* b1  = (const float*)d_in[3];
    const float* Wmu = (const float*)d_in[4];
    const float* bmu = (const float*)d_in[5];
    const float* Wls = (const float*)d_in[6];
    const float* bls = (const float*)d_in[7];

    const int N = in_sizes[0] / 128;
    const int E = in_sizes[1] / 2;
    const int* row = ei;            // sources
    const int* col = ei + E;        // targets
    const int B = (N + 63) >> SH;   // coarse buckets (<= BMAX)
    const size_t BCAP = (size_t)B * CAP;
    const size_t PL = (size_t)16 * N;   // one bf16 [N][32] plane, in 4B units

    // ws layout (4B units), no overlays:
    // ccur[1024] | binned[BCAP] | srcidx ushort[BCAP] (BCAP/2) |
    // t_lo[PL] | t_hi[PL] | dinv[N] | range2 int2[N] | agg_lo f32[32N] | agg_hi f32[32N]
    int* wsi = (int*)d_ws;
    size_t off = 0;
    int* ccur = wsi + off;                                 off += 1024;
    unsigned* binned = (unsigned*)(wsi + off);             off += BCAP;
    unsigned short* srcidx = (unsigned short*)(wsi + off); off += BCAP / 2;
    unsigned short* t_lo = (unsigned short*)(wsi + off);   off += PL;
    unsigned short* t_hi = (unsigned short*)(wsi + off);   off += PL;
    float* dinv = (float*)(wsi + off);                     off += N;
    int2* range2 = (int2*)(wsi + off);                     off += 2 * (size_t)N;
    float* agg_lo = (float*)(wsi + off);                   off += 32 * (size_t)N;
    float* agg_hi = (float*)(wsi + off);                   off += 32 * (size_t)N;
    float* outp = (float*)d_out;

    const int GG = (2 * N * 4 + 255) / 256;
    const int ntiles = (N + 63) / 64;

    (void)hipMemsetAsync(ccur, 0, 1024 * sizeof(int), stream);
    k_bin<<<(E + CHUNK - 1) / CHUNK, 256, 0, stream>>>(row, col, ccur, binned, E, B);
    k_fine<<<B, 256, 0, stream>>>(binned, ccur, srcidx, range2, dinv, N);

    k_gemm<128, false, false, false><<<ntiles, 256, 0, stream>>>(
        x, nullptr, W1, nullptr, dinv, t_lo, t_hi, N);
    k_gather<false><<<GG, 256, 0, stream>>>(
        range2, srcidx, (const uint4*)t_lo, (const uint4*)t_hi, dinv,
        b1, b1 + 32, agg_lo, agg_hi, N);

    k_gemm<64, true, true, true><<<ntiles, 256, 0, stream>>>(
        agg_lo, agg_hi, Wmu, Wls, dinv, t_lo, t_hi, N);
    k_gather<true><<<GG, 256, 0, stream>>>(
        range2, srcidx, (const uint4*)t_lo, (const uint4*)t_hi, dinv,
        bmu, bls, outp, outp + 32 * (size_t)N, N);
}

// Round 14
// 231.297 us; speedup vs baseline: 2.6841x; 1.0587x over previous
//
#include <hip/hip_runtime.h>
#include <hip/hip_bf16.h>

// GCN VGAE encoder, 7 dispatches:
//   memset ccur | k_bin (128-node buckets, 2048-edge chunks) | k_fine (128-scan) |
//   k_gemm1 | k_gather<L1, XCD-parity planes> | k_gemm2 | k_gather<L2 -> out>
// norm factorization: agg[c] = dinv[c]*(sum_e ts[src] + ts[c]) + b, ts = (X@W)*dinv.
// Notes: coop grid.sync ~75us each on MI355X (R11); gather+gemm block fusion blows
// VGPRs to 236 (R12); merged both-plane gathers thrash per-XCD L2 unless planes are
// pinned by XCD parity (R13).

constexpr int SH = 7;            // nodes per coarse bucket = 128
constexpr int NB = 1 << SH;      // 128
constexpr int CAP = 6144;        // slab capacity (mean ~4093, ~32 sigma)
constexpr int BMAX = 512;        // max buckets (N <= 65536)
constexpr int CHUNK = 2048;      // edges per block in k_bin (782 blocks ~ 3/CU)
constexpr int EPB = CHUNK / 256; // 8 register-cached edges/thread in k_bin
constexpr int EPT = 16;          // register-cached edges/thread in k_fine

typedef float vf4 __attribute__((ext_vector_type(4)));   // for nontemporal stores

__device__ __forceinline__ void fma4(float4& a, float s, const float4& w) {
    a.x = fmaf(s, w.x, a.x);
    a.y = fmaf(s, w.y, a.y);
    a.z = fmaf(s, w.z, a.z);
    a.w = fmaf(s, w.w, a.w);
}

__device__ __forceinline__ unsigned short f2bf(float f) {  // RNE
    unsigned u = __float_as_uint(f);
    return (unsigned short)((u + 0x7fffu + ((u >> 16) & 1u)) >> 16);
}

__device__ __forceinline__ void acc_bf8(float* a, uint4 v) {
    a[0] += __uint_as_float(v.x << 16);
    a[1] += __uint_as_float(v.x & 0xffff0000u);
    a[2] += __uint_as_float(v.y << 16);
    a[3] += __uint_as_float(v.y & 0xffff0000u);
    a[4] += __uint_as_float(v.z << 16);
    a[5] += __uint_as_float(v.z & 0xffff0000u);
    a[6] += __uint_as_float(v.w << 16);
    a[7] += __uint_as_float(v.w & 0xffff0000u);
}

// Sum of one (node, quad) stripe of a 32-feat bf16 plane into a[8] (fp32),
// including the self loop. 8-edge unroll for MLP.
__device__ __forceinline__ void gather_core(const int2* __restrict__ range2,
                                            const unsigned short* __restrict__ srcidx,
                                            const uint4* __restrict__ Tp,
                                            int n, int q, float* a) {
    int2 rg = range2[n];
    int k = rg.x, end = rg.y;
    {
        uint4 s = Tp[(size_t)n * 4 + q];   // self loop
        a[0] = __uint_as_float(s.x << 16);
        a[1] = __uint_as_float(s.x & 0xffff0000u);
        a[2] = __uint_as_float(s.y << 16);
        a[3] = __uint_as_float(s.y & 0xffff0000u);
        a[4] = __uint_as_float(s.z << 16);
        a[5] = __uint_as_float(s.z & 0xffff0000u);
        a[6] = __uint_as_float(s.w << 16);
        a[7] = __uint_as_float(s.w & 0xffff0000u);
    }
    for (; k < end && (k & 3); ++k)          // align to ushort4
        acc_bf8(a, Tp[(size_t)srcidx[k] * 4 + q]);
    for (; k + 8 <= end; k += 8) {
        ushort4 r0 = *reinterpret_cast<const ushort4*>(srcidx + k);
        ushort4 r1 = *reinterpret_cast<const ushort4*>(srcidx + k + 4);
        uint4 v0 = Tp[(size_t)r0.x * 4 + q];
        uint4 v1 = Tp[(size_t)r0.y * 4 + q];
        uint4 v2 = Tp[(size_t)r0.z * 4 + q];
        uint4 v3 = Tp[(size_t)r0.w * 4 + q];
        uint4 v4 = Tp[(size_t)r1.x * 4 + q];
        uint4 v5 = Tp[(size_t)r1.y * 4 + q];
        uint4 v6 = Tp[(size_t)r1.z * 4 + q];
        uint4 v7 = Tp[(size_t)r1.w * 4 + q];
        acc_bf8(a, v0); acc_bf8(a, v1); acc_bf8(a, v2); acc_bf8(a, v3);
        acc_bf8(a, v4); acc_bf8(a, v5); acc_bf8(a, v6); acc_bf8(a, v7);
    }
    if (k + 4 <= end) {
        ushort4 r0 = *reinterpret_cast<const ushort4*>(srcidx + k);
        uint4 v0 = Tp[(size_t)r0.x * 4 + q];
        uint4 v1 = Tp[(size_t)r0.y * 4 + q];
        uint4 v2 = Tp[(size_t)r0.z * 4 + q];
        uint4 v3 = Tp[(size_t)r0.w * 4 + q];
        acc_bf8(a, v0); acc_bf8(a, v1); acc_bf8(a, v2); acc_bf8(a, v3);
        k += 4;
    }
    for (; k < end; ++k)
        acc_bf8(a, Tp[(size_t)srcidx[k] * 4 + q]);
}

// ---------------- k_bin ----------------
// Single global read; edges register-cached as col16<<16|row16; LDS hist ->
// reserve slab slice via ccur atomic -> emit. Bucket = packed>>(16+SH).
__global__ __launch_bounds__(256) void k_bin(const int* __restrict__ row,
                                             const int* __restrict__ col,
                                             int* __restrict__ ccur,
                                             unsigned* __restrict__ binned,
                                             int E, int B) {
    __shared__ int h[BMAX];
    const int tid = threadIdx.x;
    for (int i = tid; i < B; i += 256) h[i] = 0;
    __syncthreads();
    const int e0 = blockIdx.x * CHUNK;
    unsigned ebuf[EPB];
    #pragma unroll
    for (int j = 0; j < EPB; ++j) {
        int e = e0 + tid + j * 256;
        ebuf[j] = (e < E) ? (((unsigned)col[e] << 16) | (unsigned)row[e]) : 0xFFFFFFFFu;
    }
    #pragma unroll
    for (int j = 0; j < EPB; ++j)
        if (ebuf[j] != 0xFFFFFFFFu) atomicAdd(&h[ebuf[j] >> (16 + SH)], 1);
    __syncthreads();
    for (int i = tid; i < B; i += 256) {
        int c = h[i];
        if (c) h[i] = atomicAdd(&ccur[i], c);   // in-bucket base for this block
    }
    __syncthreads();
    #pragma unroll
    for (int j = 0; j < EPB; ++j) {
        unsigned e = ebuf[j];
        if (e != 0xFFFFFFFFu) {
            int b = e >> (16 + SH);
            int pos = atomicAdd(&h[b], 1);
            if (pos < CAP) binned[(size_t)b * CAP + pos] = e;
        }
    }
}

// ---------------- k_fine ----------------
// One block per 128-node bucket: register-cached entries; fine histogram -> dinv +
// (start,end) ranges (two-wave scan over 128); dense ushort srcidx emit.
__global__ __launch_bounds__(256) void k_fine(const unsigned* __restrict__ binned,
                                              const int* __restrict__ ccur,
                                              unsigned short* __restrict__ srcidx,
                                              int2* __restrict__ range2,
                                              float* __restrict__ dinv, int N) {
    __shared__ int fine[NB];
    __shared__ int w0tot;
    const int b = blockIdx.x;
    const int n0 = b << SH;
    const int ebase = b * CAP;
    const int ecnt = min(ccur[b], CAP);
    const int tid = threadIdx.x;
    if (tid < NB) fine[tid] = 0;
    __syncthreads();
    unsigned ebuf[EPT];
    #pragma unroll
    for (int j = 0; j < EPT; ++j) {
        int i = tid + j * 256;
        ebuf[j] = (i < ecnt) ? binned[ebase + i] : 0xFFFFFFFFu;
    }
    #pragma unroll
    for (int j = 0; j < EPT; ++j)
        if (ebuf[j] != 0xFFFFFFFFu) atomicAdd(&fine[(ebuf[j] >> 16) & (NB - 1)], 1);
    for (int i = EPT * 256 + tid; i < ecnt; i += 256)   // overflow tail
        atomicAdd(&fine[(binned[ebase + i] >> 16) & (NB - 1)], 1);
    __syncthreads();
    // exclusive scan over 128 counts: per-wave inclusive scan, wave1 += wave0 total
    int v = (tid < NB) ? fine[tid] : 0;
    int s = v;
    const int lane = tid & 63;
    #pragma unroll
    for (int off = 1; off < 64; off <<= 1) {
        int u = __shfl_up(s, off, 64);
        if (lane >= off) s += u;
    }
    if (tid == 63) w0tot = s;
    __syncthreads();
    if (tid >= 64 && tid < NB) s += w0tot;
    if (tid < NB) {
        int base = ebase + s - v;
        int n = n0 + tid;
        if (n < N) {
            range2[n] = make_int2(base, base + v);
            dinv[n] = rsqrtf((float)v + 1.0f);
        }
        fine[tid] = base;
    }
    __syncthreads();
    #pragma unroll
    for (int j = 0; j < EPT; ++j) {
        unsigned e = ebuf[j];
        if (e != 0xFFFFFFFFu) {
            int pos = atomicAdd(&fine[(e >> 16) & (NB - 1)], 1);
            srcidx[pos] = (unsigned short)(e & 0xFFFFu);
        }
    }
    for (int i = EPT * 256 + tid; i < ecnt; i += 256) {
        unsigned e = binned[ebase + i];
        int pos = atomicAdd(&fine[(e >> 16) & (NB - 1)], 1);
        srcidx[pos] = (unsigned short)(e & 0xFFFFu);
    }
}

// ---------------- k_gemm ----------------
// T planes (bf16 [N][32] x2) = (op(X) @ W) * dinv[n]. 4 nodes/thread, 64-node tiles.
// PIN: X given as two fp32 [N][32] planes (layer 2); else contiguous [N][K].
template <int K, bool RELU, bool TWO_W, bool PIN>
__global__ __launch_bounds__(256) void k_gemm(const float* __restrict__ X,
                                              const float* __restrict__ Xhi,
                                              const float* __restrict__ Wa,
                                              const float* __restrict__ Wb,
                                              const float* __restrict__ dinv,
                                              unsigned short* __restrict__ Tlo,
                                              unsigned short* __restrict__ Thi, int N) {
    __shared__ float4 Wl[K * 16];
    const int tid = threadIdx.x;
    for (int i = tid; i < K * 16; i += 256) {
        if (TWO_W) {
            int k = i >> 4, fgi = i & 15;
            const float* s = (fgi < 8) ? (Wa + k * 32 + fgi * 4)
                                       : (Wb + k * 32 + (fgi - 8) * 4);
            Wl[i] = *reinterpret_cast<const float4*>(s);
        } else {
            Wl[i] = reinterpret_cast<const float4*>(Wa)[i];
        }
    }
    __syncthreads();

    const int fg = tid & 15;
    const int ns = tid >> 4;
    const int nb = blockIdx.x * 64;
    const float4* Xv = reinterpret_cast<const float4*>(X);
    const float4* Xv2 = reinterpret_cast<const float4*>(Xhi);
    const float4 z = make_float4(0.f, 0.f, 0.f, 0.f);
    float4 acc[4] = {z, z, z, z};
    int n[4];
    bool v[4];
    #pragma unroll
    for (int i = 0; i < 4; ++i) { n[i] = nb + ns + i * 16; v[i] = n[i] < N; }

    for (int k4 = 0; k4 < K / 4; ++k4) {
        float4 xv[4];
        #pragma unroll
        for (int i = 0; i < 4; ++i) {
            if (PIN)
                xv[i] = v[i] ? ((k4 < 8) ? Xv[(size_t)n[i] * 8 + k4]
                                         : Xv2[(size_t)n[i] * 8 + (k4 - 8)]) : z;
            else
                xv[i] = v[i] ? Xv[(size_t)n[i] * (K / 4) + k4] : z;
            if (RELU) {
                xv[i].x = fmaxf(xv[i].x, 0.f); xv[i].y = fmaxf(xv[i].y, 0.f);
                xv[i].z = fmaxf(xv[i].z, 0.f); xv[i].w = fmaxf(xv[i].w, 0.f);
            }
        }
        float4 w0 = Wl[(k4 * 4 + 0) * 16 + fg];
        float4 w1 = Wl[(k4 * 4 + 1) * 16 + fg];
        float4 w2 = Wl[(k4 * 4 + 2) * 16 + fg];
        float4 w3 = Wl[(k4 * 4 + 3) * 16 + fg];
        #pragma unroll
        for (int i = 0; i < 4; ++i) {
            fma4(acc[i], xv[i].x, w0); fma4(acc[i], xv[i].y, w1);
            fma4(acc[i], xv[i].z, w2); fma4(acc[i], xv[i].w, w3);
        }
    }
    ushort4* Tp = reinterpret_cast<ushort4*>((fg < 8) ? Tlo : Thi);
    const int j = fg & 7;
    #pragma unroll
    for (int i = 0; i < 4; ++i) {
        if (v[i]) {
            float d = dinv[n[i]];
            ushort4 o;
            o.x = f2bf(acc[i].x * d); o.y = f2bf(acc[i].y * d);
            o.z = f2bf(acc[i].z * d); o.w = f2bf(acc[i].w * d);
            Tp[(size_t)n[i] * 8 + j] = o;
        }
    }
}

// ---------------- k_gather ----------------
// Both planes of one layer in a single dispatch, plane pinned by XCD parity:
// plane = blockIdx&1 (round-robin block->XCD mapping keeps each XCD on one 3.2MB
// plane -> per-XCD L2-resident). Grid = 2 * ceil(N*4/256).
template <bool NT>
__global__ __launch_bounds__(256) void k_gather(
    const int2* __restrict__ range2, const unsigned short* __restrict__ srcidx,
    const uint4* __restrict__ Tlo, const uint4* __restrict__ Thi,
    const float* __restrict__ dinv,
    const float* __restrict__ bias_lo, const float* __restrict__ bias_hi,
    float* __restrict__ dst_lo, float* __restrict__ dst_hi, int N) {
    const int plane = blockIdx.x & 1;
    int idx = (blockIdx.x >> 1) * 256 + threadIdx.x;
    if (idx >= N * 4) return;
    int n = idx >> 2, q = idx & 3;
    float a[8];
    gather_core(range2, srcidx, plane ? Thi : Tlo, n, q, a);
    float d = dinv[n];
    const float* bias = (plane ? bias_hi : bias_lo) + q * 8;
    float* dst = (plane ? dst_hi : dst_lo) + (size_t)n * 32 + q * 8;
    float4 b0 = reinterpret_cast<const float4*>(bias)[0];
    float4 b1 = reinterpret_cast<const float4*>(bias)[1];
    vf4 o0, o1;
    o0.x = fmaf(a[0], d, b0.x); o0.y = fmaf(a[1], d, b0.y);
    o0.z = fmaf(a[2], d, b0.z); o0.w = fmaf(a[3], d, b0.w);
    o1.x = fmaf(a[4], d, b1.x); o1.y = fmaf(a[5], d, b1.y);
    o1.z = fmaf(a[6], d, b1.z); o1.w = fmaf(a[7], d, b1.w);
    if (NT) {
        __builtin_nontemporal_store(o0, reinterpret_cast<vf4*>(dst));
        __builtin_nontemporal_store(o1, reinterpret_cast<vf4*>(dst) + 1);
    } else {
        reinterpret_cast<vf4*>(dst)[0] = o0;
        reinterpret_cast<vf4*>(dst)[1] = o1;
    }
}

extern "C" void kernel_launch(void* const* d_in, const int* in_sizes, int n_in,
                              void* d_out, int out_size, void* d_ws, size_t ws_size,
                              hipStream_t stream) {
    const float* x   = (const float*)d_in[0];
    const int*   ei  = (const int*)d_in[1];
    const float* W1  = (const float*)d_in[2];
    const float* b1  = (const float*)d_in[3];
    const float* Wmu = (const float*)d_in[4];
    const float* bmu = (const float*)d_in[5];
    const float* Wls = (const float*)d_in[6];
    const float* bls = (const float*)d_in[7];

    const int N = in_sizes[0] / 128;
    const int E = in_sizes[1] / 2;
    const int* row = ei;             // sources
    const int* col = ei + E;         // targets
    const int B = (N + NB - 1) >> SH;   // 128-node buckets (<= BMAX)
    const size_t BCAP = (size_t)B * CAP;
    const size_t PL = (size_t)16 * N;   // one bf16 [N][32] plane, in 4B units

    // ws layout (4B units), no overlays:
    // ccur[512] | binned[BCAP] | srcidx ushort[BCAP] (BCAP/2) |
    // t_lo[PL] | t_hi[PL] | dinv[N] | range2 int2[N] | agg_lo f32[32N] | agg_hi f32[32N]
    int* wsi = (int*)d_ws;
    size_t off = 0;
    int* ccur = wsi + off;                                 off += BMAX;
    unsigned* binned = (unsigned*)(wsi + off);             off += BCAP;
    unsigned short* srcidx = (unsigned short*)(wsi + off); off += BCAP / 2;
    unsigned short* t_lo = (unsigned short*)(wsi + off);   off += PL;
    unsigned short* t_hi = (unsigned short*)(wsi + off);   off += PL;
    float* dinv = (float*)(wsi + off);                     off += N;
    int2* range2 = (int2*)(wsi + off);                     off += 2 * (size_t)N;
    float* agg_lo = (float*)(wsi + off);                   off += 32 * (size_t)N;
    float* agg_hi = (float*)(wsi + off);                   off += 32 * (size_t)N;
    float* outp = (float*)d_out;

    const int GG = 2 * ((N * 4 + 255) / 256);   // both planes, parity-split
    const int ntiles = (N + 63) / 64;

    (void)hipMemsetAsync(ccur, 0, BMAX * sizeof(int), stream);
    k_bin<<<(E + CHUNK - 1) / CHUNK, 256, 0, stream>>>(row, col, ccur, binned, E, B);
    k_fine<<<B, 256, 0, stream>>>(binned, ccur, srcidx, range2, dinv, N);

    k_gemm<128, false, false, false><<<ntiles, 256, 0, stream>>>(
        x, nullptr, W1, nullptr, dinv, t_lo, t_hi, N);
    k_gather<false><<<GG, 256, 0, stream>>>(
        range2, srcidx, (const uint4*)t_lo, (const uint4*)t_hi, dinv,
        b1, b1 + 32, agg_lo, agg_hi, N);

    k_gemm<64, true, true, true><<<ntiles, 256, 0, stream>>>(
        agg_lo, agg_hi, Wmu, Wls, dinv, t_lo, t_hi, N);
    k_gather<true><<<GG, 256, 0, stream>>>(
        range2, srcidx, (const uint4*)t_lo, (const uint4*)t_hi, dinv,
        bmu, bls, outp, outp + 32 * (size_t)N, N);
}